// Round 10
// baseline (2218.588 us; speedup 1.0000x reference)
//
#include <hip/hip_runtime.h>

typedef _Float16 f16;
typedef _Float16 f16x8 __attribute__((ext_vector_type(8)));
typedef float f32x4 __attribute__((ext_vector_type(4)));

#define N_ROWS 500000
#define EPS_LOG 1e-7f
#define EPS_LN  1e-5f
#define RPB 96          // rows per block
#define NTHREADS 192    // 3 waves

// ws layout (819200 bytes total, proven safe):
//   f16 idx [0, 10240)      : W1p [256][40]
//   bytes [20480, 32768)    : f32 cst: [0,256)=w8g, [256]=s8, [257]=cb8,
//                             [1536+li*256+j)=bb (layers 2..7)
//   f16 idx [16384, 409600) : Wg layers 2..7 slab-permuted (16KB per K-step)
#define CST_BYTE_OFF 20480

__device__ __forceinline__ void gload_lds16(const f16* g, f16* l) {
  __builtin_amdgcn_global_load_lds(
      (const __attribute__((address_space(1))) void*)g,
      (__attribute__((address_space(3))) void*)l, 16, 0, 0);
}

// ---------------- prep (r8/r9-proven) ----------------
__global__ void prep_kernel(const float* __restrict__ W1,
                            const float* __restrict__ W2, const float* __restrict__ W3,
                            const float* __restrict__ W4, const float* __restrict__ W5,
                            const float* __restrict__ W6, const float* __restrict__ W7,
                            const float* __restrict__ W8, const float* __restrict__ b8,
                            const float* __restrict__ b2, const float* __restrict__ b3,
                            const float* __restrict__ b4, const float* __restrict__ b5,
                            const float* __restrict__ b6, const float* __restrict__ b7,
                            const float* __restrict__ gamma, const float* __restrict__ beta,
                            f16* __restrict__ ws) {
  float* cstF = (float*)((char*)ws + CST_BYTE_OFF);
  int idx = blockIdx.x * 256 + threadIdx.x;
  if (idx < 10240) {
    int j = idx / 40, k = idx - j * 40;
    ws[idx] = (f16)((k < 39) ? W1[j * 39 + k] : 0.0f);
  } else if (idx < 16384) {
    // cst region — written below
  } else if (idx < 409600) {
    int o = idx - 16384;
    int li = o >> 16;  o &= 65535;
    const float* W = (li == 0) ? W2 : (li == 1) ? W3 : (li == 2) ? W4
                   : (li == 3) ? W5 : (li == 4) ? W6 : W7;
    int e = o & 7, j = (o >> 3) & 255, kgrp = (o >> 11) & 3, kt = o >> 13;
    int k = kt * 32 + kgrp * 8 + e;
    ws[idx] = (f16)(W[j * 256 + k] * gamma[k]);
  } else if (idx < 411136) {
    int o = idx - 409600;
    int li = o >> 8, j = o & 255;
    const float* W = (li == 0) ? W2 : (li == 1) ? W3 : (li == 2) ? W4
                   : (li == 3) ? W5 : (li == 4) ? W6 : W7;
    const float* b = (li == 0) ? b2 : (li == 1) ? b3 : (li == 2) ? b4
                   : (li == 3) ? b5 : (li == 4) ? b6 : b7;
    float bb = 0.f;
    for (int k = 0; k < 256; ++k) bb = fmaf(W[j * 256 + k], beta[k], bb);
    cstF[1536 + li * 256 + j] = bb + b[j];
  } else if (idx < 411392) {
    int j = idx - 411136;
    cstF[j] = W8[j] * gamma[j];
  } else if (idx == 411392) {
    float s8 = 0.f, cb = 0.f;
    for (int k = 0; k < 256; ++k) {
      float w = W8[k];
      s8 = fmaf(w, gamma[k], s8);
      cb = fmaf(w, beta[k], cb);
    }
    cstF[256] = s8;
    cstF[257] = cb + b8[0];
  }
}

// ---------------- fused MLP: zero-reg DMA staging, dbuf slab, 1 barrier/K-step ----
// 192 threads = 3 waves; 96 rows/block; wave owns rows [wid*32, wid*32+32).
// All hbuf traffic wave-private at row-stride 256 (r5-proven race-free).
// Slab staged via global_load_lds (zero registers -> no spill; acc=128 AGPR +
// ~100 arch fits the 256 cap at 2 waves/SIMD). r6 lesson: __syncthreads alone
// does NOT reliably drain the LDS-DMA -> explicit vmcnt(0) before each barrier.
// Double buffer + single barrier per step: [vmcnt0;barrier] -> stage(kt+1 ->
// buf^1) -> compute(kt <- buf). buf^1's last readers (compute kt-1) are
// pre-barrier => no race; DMA latency hides under compute.
__global__ __launch_bounds__(NTHREADS)
__attribute__((amdgpu_waves_per_eu(2)))
void mlp_kernel(const float* __restrict__ x, const f16* __restrict__ wsw,
                const float* __restrict__ b1, float* __restrict__ out) {
  __shared__ __attribute__((aligned(16))) f16 hbuf[RPB * 256];   // 48 KB
  __shared__ __attribute__((aligned(16))) f16 wslab[2][8192];    // 32 KB

  const float* cstF = (const float*)((const char*)wsw + CST_BYTE_OFF);
  const int t = threadIdx.x;
  const int lane = t & 63;
  const int wid = t >> 6;          // 0..2
  const int lm = lane & 15;
  const int lg = lane >> 4;
  const long rowbase = (long)blockIdx.x * RPB;
  const int R0 = wid * 32;
  const int myrow0 = R0 + lm;
  const int myrow1 = R0 + 16 + lm;
  const int sA0 = ((myrow0 >> 1) & 7) << 3;
  const int sA1 = ((myrow1 >> 1) & 7) << 3;

  // 16KB slab = 16 wave-issues of 1KB; waves split them round-robin.
  auto stage = [&](int buf, const f16* g) {
    for (int c = wid; c < 16; c += 3)
      gload_lds16(g + c * 512 + lane * 8, &wslab[buf][c * 512 + lane * 8]);
  };

  const f16* WgBase = wsw + 16384;
  stage(0, WgBase);                // slab (layer2, kt0) in flight from the start

  // ---- input fill (wave-private, stride 256, swizzled, zero-padded) ----
  #pragma unroll 1
  for (int i = 0; i < 32; ++i) {
    int r = R0 + i;
    long gr = rowbase + r;
    float tv = 0.0f;
    if (lane < 39) {
      float xv = (gr < N_ROWS) ? x[gr * 39 + lane] : 1.0f;
      tv = 0.1f * __logf(xv + EPS_LOG);
    }
    hbuf[r * 256 + (lane ^ (((r >> 1) & 7) << 3))] = (f16)tv;
  }

  f32x4 acc0[16], acc1[16];

  auto compute = [&](int kt, const f16* wsl) {
    f16x8 av0 = *(const f16x8*)&hbuf[myrow0 * 256 + ((kt * 32 + lg * 8) ^ sA0)];
    f16x8 av1 = *(const f16x8*)&hbuf[myrow1 * 256 + ((kt * 32 + lg * 8) ^ sA1)];
    #pragma unroll
    for (int nt = 0; nt < 16; ++nt) {
      f16x8 bf = *(const f16x8*)&wsl[lg * 2048 + (nt * 16 + lm) * 8];
      acc0[nt] = __builtin_amdgcn_mfma_f32_16x16x32_f16(av0, bf, acc0[nt], 0, 0, 0);
      acc1[nt] = __builtin_amdgcn_mfma_f32_16x16x32_f16(av1, bf, acc1[nt], 0, 0, 0);
    }
  };

  // epilogue (r7-proven): lane (lg,lm) holds acc[nt][i] = row rbase+lg*4+i,
  // col nt*16+lm. Store z=(a-mu)*is to wave-private hbuf rows.
  auto do_tile = [&](f32x4* acc, int rbase, bool tanh_act, const float* cvec) {
    float nm[4] = {0, 0, 0, 0}, nq[4] = {0, 0, 0, 0};
    #pragma unroll
    for (int nt = 0; nt < 16; ++nt) {
      float c0 = cvec[nt * 16 + lm];
      #pragma unroll
      for (int i = 0; i < 4; ++i) {
        float v = acc[nt][i] + c0;
        float a;
        if (tanh_act) {
          float e2 = __expf(2.f * v);
          a = 1.f - 2.f / (e2 + 1.f);
        } else {
          a = (v > 0.f) ? v : (__expf(v) - 1.f);
        }
        acc[nt][i] = a;
        nm[i] += a;
        nq[i] = fmaf(a, a, nq[i]);
      }
    }
    #pragma unroll
    for (int off = 1; off < 16; off <<= 1) {
      #pragma unroll
      for (int i = 0; i < 4; ++i) {
        nm[i] += __shfl_xor(nm[i], off, 64);
        nq[i] += __shfl_xor(nq[i], off, 64);
      }
    }
    float mu[4], is_[4];
    #pragma unroll
    for (int i = 0; i < 4; ++i) {
      float m = nm[i] * (1.f / 256.f);
      float var = nq[i] * (1.f / 256.f) - m * m;
      mu[i] = m;
      is_[i] = rsqrtf(var + EPS_LN);
    }
    #pragma unroll
    for (int nt = 0; nt < 16; ++nt) {
      int col = nt * 16 + lm;
      #pragma unroll
      for (int i = 0; i < 4; ++i) {
        int r = rbase + lg * 4 + i;
        hbuf[r * 256 + (col ^ (((r >> 1) & 7) << 3))] =
            (f16)((acc[nt][i] - mu[i]) * is_[i]);
      }
    }
  };

  // layer-7 epilogue fused with layer 8 (r9-proven)
  auto final_tile = [&](f32x4* acc, int rbase) {
    const float* bb7 = cstF + 1536 + 5 * 256;
    float s8 = cstF[256], cb8 = cstF[257];
    float nm[4] = {0, 0, 0, 0}, nq[4] = {0, 0, 0, 0}, dt[4] = {0, 0, 0, 0};
    #pragma unroll
    for (int nt = 0; nt < 16; ++nt) {
      float c0 = bb7[nt * 16 + lm];
      float w8 = cstF[nt * 16 + lm];
      #pragma unroll
      for (int i = 0; i < 4; ++i) {
        float v = acc[nt][i] + c0;
        float a = (v > 0.f) ? v : (__expf(v) - 1.f);
        nm[i] += a;
        nq[i] = fmaf(a, a, nq[i]);
        dt[i] = fmaf(a, w8, dt[i]);
      }
    }
    #pragma unroll
    for (int off = 1; off < 16; off <<= 1) {
      #pragma unroll
      for (int i = 0; i < 4; ++i) {
        nm[i] += __shfl_xor(nm[i], off, 64);
        nq[i] += __shfl_xor(nq[i], off, 64);
        dt[i] += __shfl_xor(dt[i], off, 64);
      }
    }
    if (lm == 0) {
      #pragma unroll
      for (int i = 0; i < 4; ++i) {
        float mu = nm[i] * (1.f / 256.f);
        float is = rsqrtf(nq[i] * (1.f / 256.f) - mu * mu + EPS_LN);
        long gr = rowbase + rbase + lg * 4 + i;
        if (gr < N_ROWS) out[gr] = fmaf(is, dt[i] - mu * s8, cb8);
      }
    }
  };

  // ================= layer 1: z1 = LN-norm(tanh(t @ W1^T + b1)), K=64 =============
  {
    #pragma unroll
    for (int i = 0; i < 16; ++i) { acc0[i] = (f32x4){0,0,0,0}; acc1[i] = (f32x4){0,0,0,0}; }
    #pragma unroll
    for (int kt = 0; kt < 2; ++kt) {
      f16x8 av0 = *(const f16x8*)&hbuf[myrow0 * 256 + ((kt * 32 + lg * 8) ^ sA0)];
      f16x8 av1 = *(const f16x8*)&hbuf[myrow1 * 256 + ((kt * 32 + lg * 8) ^ sA1)];
      #pragma unroll
      for (int nt = 0; nt < 16; ++nt) {
        int j40 = (nt * 16 + lm) * 40;
        f16x8 bf = 0;
        if (kt == 0)       bf = *(const f16x8*)&wsw[j40 + lg * 8];
        else if (lg == 0)  bf = *(const f16x8*)&wsw[j40 + 32];
        acc0[nt] = __builtin_amdgcn_mfma_f32_16x16x32_f16(av0, bf, acc0[nt], 0, 0, 0);
        acc1[nt] = __builtin_amdgcn_mfma_f32_16x16x32_f16(av1, bf, acc1[nt], 0, 0, 0);
      }
    }
    do_tile(acc0, R0,      true, b1);
    do_tile(acc1, R0 + 16, true, b1);
  }

  // ================= layers 2..7 =================
  #pragma unroll 1
  for (int li = 0; li < 6; ++li) {
    const f16* Wb = WgBase + li * 65536;
    #pragma unroll
    for (int i = 0; i < 16; ++i) { acc0[i] = (f32x4){0,0,0,0}; acc1[i] = (f32x4){0,0,0,0}; }
    #pragma unroll 1
    for (int kt = 0; kt < 8; ++kt) {
      // PUBLISH: per-wave DMA for slab kt drained, then barrier; also retires
      // all waves' reads of buf (kt+1)&1 (their compute(kt-1) is pre-barrier).
      asm volatile("s_waitcnt vmcnt(0)" ::: "memory");
      __syncthreads();
      __builtin_amdgcn_sched_barrier(0);
      if (kt < 7)       stage((kt + 1) & 1, Wb + (kt + 1) * 8192);
      else if (li < 5)  stage((kt + 1) & 1, Wb + 65536);
      compute(kt, wslab[kt & 1]);
    }
    if (li < 5) {
      do_tile(acc0, R0,      false, cstF + 1536 + li * 256);
      do_tile(acc1, R0 + 16, false, cstF + 1536 + li * 256);
    } else {
      final_tile(acc0, R0);
      final_tile(acc1, R0 + 16);
    }
  }
}

extern "C" void kernel_launch(void* const* d_in, const int* in_sizes, int n_in,
                              void* d_out, int out_size, void* d_ws, size_t ws_size,
                              hipStream_t stream) {
  const float* x  = (const float*)d_in[0];
  const float* W1 = (const float*)d_in[1];
  const float* b1 = (const float*)d_in[2];
  const float* W2 = (const float*)d_in[3];
  const float* b2 = (const float*)d_in[4];
  const float* W3 = (const float*)d_in[5];
  const float* b3 = (const float*)d_in[6];
  const float* W4 = (const float*)d_in[7];
  const float* b4 = (const float*)d_in[8];
  const float* W5 = (const float*)d_in[9];
  const float* b5 = (const float*)d_in[10];
  const float* W6 = (const float*)d_in[11];
  const float* b6 = (const float*)d_in[12];
  const float* W7 = (const float*)d_in[13];
  const float* b7 = (const float*)d_in[14];
  const float* W8 = (const float*)d_in[15];
  const float* b8 = (const float*)d_in[16];
  const float* gm = (const float*)d_in[17];
  const float* bt = (const float*)d_in[18];
  f16* ws = (f16*)d_ws;
  float* out = (float*)d_out;

  prep_kernel<<<1608, 256, 0, stream>>>(W1, W2, W3, W4, W5, W6, W7, W8, b8,
                                        b2, b3, b4, b5, b6, b7, gm, bt, ws);

  int nblk = (N_ROWS + RPB - 1) / RPB;   // 5209
  mlp_kernel<<<nblk, NTHREADS, 0, stream>>>(x, ws, b1, out);
}

// Round 11
// 1041.538 us; speedup vs baseline: 2.1301x; 2.1301x over previous
//
#include <hip/hip_runtime.h>

typedef _Float16 f16;
typedef _Float16 f16x8 __attribute__((ext_vector_type(8)));
typedef float f32x4 __attribute__((ext_vector_type(4)));

#define N_ROWS 500000
#define EPS_LOG 1e-7f
#define EPS_LN  1e-5f

// ws layout (819200 bytes total, proven safe):
//   f16 idx [0, 10240)      : W1p [256][40]
//   bytes [20480, 32768)    : f32 cst: [0,256)=w8g, [256]=s8, [257]=cb8,
//                             [1536+li*256+j]=bb (layers 2..7)
//   f16 idx [16384, 409600) : Wg layers 2..7 slab-permuted (16KB per K-step):
//       idx = 16384 + li*65536 + kt*8192 + kgrp*2048 + j*8 + e,
//       value = W[j][k]*gamma[k], k = kt*32 + kgrp*8 + e
#define CST_BYTE_OFF 20480

__device__ __forceinline__ void gload_lds16(const f16* g, f16* l) {
  __builtin_amdgcn_global_load_lds(
      (const __attribute__((address_space(1))) void*)g,
      (__attribute__((address_space(3))) void*)l, 16, 0, 0);
}

// ---------------- prep (r8-r10 proven) ----------------
__global__ void prep_kernel(const float* __restrict__ W1,
                            const float* __restrict__ W2, const float* __restrict__ W3,
                            const float* __restrict__ W4, const float* __restrict__ W5,
                            const float* __restrict__ W6, const float* __restrict__ W7,
                            const float* __restrict__ W8, const float* __restrict__ b8,
                            const float* __restrict__ b2, const float* __restrict__ b3,
                            const float* __restrict__ b4, const float* __restrict__ b5,
                            const float* __restrict__ b6, const float* __restrict__ b7,
                            const float* __restrict__ gamma, const float* __restrict__ beta,
                            f16* __restrict__ ws) {
  float* cstF = (float*)((char*)ws + CST_BYTE_OFF);
  int idx = blockIdx.x * 256 + threadIdx.x;
  if (idx < 10240) {
    int j = idx / 40, k = idx - j * 40;
    ws[idx] = (f16)((k < 39) ? W1[j * 39 + k] : 0.0f);
  } else if (idx < 16384) {
    // cst region — written below
  } else if (idx < 409600) {
    int o = idx - 16384;
    int li = o >> 16;  o &= 65535;
    const float* W = (li == 0) ? W2 : (li == 1) ? W3 : (li == 2) ? W4
                   : (li == 3) ? W5 : (li == 4) ? W6 : W7;
    int e = o & 7, j = (o >> 3) & 255, kgrp = (o >> 11) & 3, kt = o >> 13;
    int k = kt * 32 + kgrp * 8 + e;
    ws[idx] = (f16)(W[j * 256 + k] * gamma[k]);
  } else if (idx < 411136) {
    int o = idx - 409600;
    int li = o >> 8, j = o & 255;
    const float* W = (li == 0) ? W2 : (li == 1) ? W3 : (li == 2) ? W4
                   : (li == 3) ? W5 : (li == 4) ? W6 : W7;
    const float* b = (li == 0) ? b2 : (li == 1) ? b3 : (li == 2) ? b4
                   : (li == 3) ? b5 : (li == 4) ? b6 : b7;
    float bb = 0.f;
    for (int k = 0; k < 256; ++k) bb = fmaf(W[j * 256 + k], beta[k], bb);
    cstF[1536 + li * 256 + j] = bb + b[j];
  } else if (idx < 411392) {
    int j = idx - 411136;
    cstF[j] = W8[j] * gamma[j];
  } else if (idx == 411392) {
    float s8 = 0.f, cb = 0.f;
    for (int k = 0; k < 256; ++k) {
      float w = W8[k];
      s8 = fmaf(w, gamma[k], s8);
      cb = fmaf(w, beta[k], cb);
    }
    cstF[256] = s8;
    cstF[257] = cb + b8[0];
  }
}

// ---------------- fused MLP: N-split waves (M=32,N=128) -> acc=64, no spill ------
// 256 threads = 4 waves = 2 M-bands x 2 N-halves; 64 rows/block.
// acc = 8 f32x4 per tile-pair = 64 regs; T ~ 175 << 256 cap -> zero spill,
// 2 waves/SIMD. Wave (mb,nh) computes rows [mb*32,+32) x cols [nh*128,+128).
// LN stats cross the N-halves -> LDS partials + 1 barrier per layer.
// Slab staged via global_load_lds (zero regs) with the r10-PROVEN schedule:
// per K-step [vmcnt(0); barrier; sched_barrier] -> stage(kt+1 -> buf^1) ->
// compute(kt <- buf). z-store -> next-layer z-read ordering comes from the
// same barriers.
__global__ __launch_bounds__(256, 2)
void mlp_kernel(const float* __restrict__ x, const f16* __restrict__ wsw,
                const float* __restrict__ b1, float* __restrict__ out) {
  __shared__ __attribute__((aligned(16))) f16 hbuf[64 * 256];    // 32 KB
  __shared__ __attribute__((aligned(16))) f16 wslab[2][8192];    // 32 KB
  __shared__ float pnm[2][64], pnq[2][64], pdt[2][64];           // 1.5 KB

  const float* cstF = (const float*)((const char*)wsw + CST_BYTE_OFF);
  const int t = threadIdx.x;
  const int lane = t & 63;
  const int wid = t >> 6;
  const int mb = wid >> 1;           // M-band 0..1
  const int nh = wid & 1;            // N-half 0..1
  const int lm = lane & 15;
  const int lg = lane >> 4;
  const long rowbase = (long)blockIdx.x * 64;
  const int R0 = mb * 32;
  const int myrow0 = R0 + lm;
  const int myrow1 = R0 + 16 + lm;
  const int sA0 = ((myrow0 >> 1) & 7) << 3;
  const int sA1 = ((myrow1 >> 1) & 7) << 3;
  const int colbase = nh * 128;

  // 16 KB slab: 256 threads x 4 chunks x 16 B (r10-proven addressing)
  auto stage = [&](int buf, const f16* g) {
    #pragma unroll
    for (int c = 0; c < 4; ++c) {
      int d = c * 256 + t;
      gload_lds16(g + d * 8, &wslab[buf][d * 8]);
    }
  };

  const f16* WgBase = wsw + 16384;
  stage(0, WgBase);                  // layer-2 slab 0 in flight from the start

  // ---- input fill: each wave fills rows [wid*16,+16) (cross-wave read later,
  //      ordered by the barrier below), stride 256, swizzled, zero-padded ----
  #pragma unroll 1
  for (int i = 0; i < 16; ++i) {
    int r = wid * 16 + i;
    long gr = rowbase + r;
    float tv = 0.0f;
    if (lane < 39) {
      float xv = (gr < N_ROWS) ? x[gr * 39 + lane] : 1.0f;
      tv = 0.1f * __logf(xv + EPS_LOG);
    }
    hbuf[r * 256 + (lane ^ (((r >> 1) & 7) << 3))] = (f16)tv;
  }
  __syncthreads();                   // fill visible to all waves

  f32x4 acc0[8], acc1[8];

  auto compute = [&](int kt, const f16* wsl) {
    f16x8 av0 = *(const f16x8*)&hbuf[myrow0 * 256 + ((kt * 32 + lg * 8) ^ sA0)];
    f16x8 av1 = *(const f16x8*)&hbuf[myrow1 * 256 + ((kt * 32 + lg * 8) ^ sA1)];
    #pragma unroll
    for (int nt = 0; nt < 8; ++nt) {
      f16x8 bf = *(const f16x8*)&wsl[lg * 2048 + (colbase + nt * 16 + lm) * 8];
      acc0[nt] = __builtin_amdgcn_mfma_f32_16x16x32_f16(av0, bf, acc0[nt], 0, 0, 0);
      acc1[nt] = __builtin_amdgcn_mfma_f32_16x16x32_f16(av1, bf, acc1[nt], 0, 0, 0);
    }
  };

  // epilogue (both M-tiles): act -> cross-wave stats via LDS partials -> z-store.
  // C layout (m89): lane (lg,lm) holds acc{0,1}[nt][i] = row R0+{0,16}+lg*4+i,
  // col colbase+nt*16+lm.
  auto do_tile = [&](bool tanh_act, const float* cvec) {
    float pm0[4] = {0,0,0,0}, pq0[4] = {0,0,0,0};
    float pm1[4] = {0,0,0,0}, pq1[4] = {0,0,0,0};
    #pragma unroll
    for (int nt = 0; nt < 8; ++nt) {
      float c0 = cvec[colbase + nt * 16 + lm];
      #pragma unroll
      for (int i = 0; i < 4; ++i) {
        float v0 = acc0[nt][i] + c0, v1 = acc1[nt][i] + c0;
        float a0, a1;
        if (tanh_act) {
          float e0 = __expf(2.f * v0), e1 = __expf(2.f * v1);
          a0 = 1.f - 2.f / (e0 + 1.f);
          a1 = 1.f - 2.f / (e1 + 1.f);
        } else {
          a0 = (v0 > 0.f) ? v0 : (__expf(v0) - 1.f);
          a1 = (v1 > 0.f) ? v1 : (__expf(v1) - 1.f);
        }
        acc0[nt][i] = a0;  acc1[nt][i] = a1;
        pm0[i] += a0;  pq0[i] = fmaf(a0, a0, pq0[i]);
        pm1[i] += a1;  pq1[i] = fmaf(a1, a1, pq1[i]);
      }
    }
    #pragma unroll
    for (int off = 1; off < 16; off <<= 1) {
      #pragma unroll
      for (int i = 0; i < 4; ++i) {
        pm0[i] += __shfl_xor(pm0[i], off, 64);
        pq0[i] += __shfl_xor(pq0[i], off, 64);
        pm1[i] += __shfl_xor(pm1[i], off, 64);
        pq1[i] += __shfl_xor(pq1[i], off, 64);
      }
    }
    if (lm == 0) {
      #pragma unroll
      for (int i = 0; i < 4; ++i) {
        pnm[nh][R0 + lg * 4 + i] = pm0[i];
        pnq[nh][R0 + lg * 4 + i] = pq0[i];
        pnm[nh][R0 + 16 + lg * 4 + i] = pm1[i];
        pnq[nh][R0 + 16 + lg * 4 + i] = pq1[i];
      }
    }
    __syncthreads();                 // both halves' partials visible
    float mu0[4], is0[4], mu1[4], is1[4];
    #pragma unroll
    for (int i = 0; i < 4; ++i) {
      int r0 = R0 + lg * 4 + i, r1 = r0 + 16;
      float m0 = (pnm[0][r0] + pnm[1][r0]) * (1.f / 256.f);
      float m1 = (pnm[0][r1] + pnm[1][r1]) * (1.f / 256.f);
      float q0 = (pnq[0][r0] + pnq[1][r0]) * (1.f / 256.f);
      float q1 = (pnq[0][r1] + pnq[1][r1]) * (1.f / 256.f);
      mu0[i] = m0;  is0[i] = rsqrtf(q0 - m0 * m0 + EPS_LN);
      mu1[i] = m1;  is1[i] = rsqrtf(q1 - m1 * m1 + EPS_LN);
    }
    #pragma unroll
    for (int nt = 0; nt < 8; ++nt) {
      int col = colbase + nt * 16 + lm;
      #pragma unroll
      for (int i = 0; i < 4; ++i) {
        int r0 = R0 + lg * 4 + i, r1 = r0 + 16;
        hbuf[r0 * 256 + (col ^ (((r0 >> 1) & 7) << 3))] =
            (f16)((acc0[nt][i] - mu0[i]) * is0[i]);
        hbuf[r1 * 256 + (col ^ (((r1 >> 1) & 7) << 3))] =
            (f16)((acc1[nt][i] - mu1[i]) * is1[i]);
      }
    }
  };

  // layer-7 epilogue fused with layer 8: out = is*(dot - mu*s8) + cb8
  auto final_tile = [&]() {
    const float* bb7 = cstF + 1536 + 5 * 256;
    float s8 = cstF[256], cb8 = cstF[257];
    float pm0[4] = {0,0,0,0}, pq0[4] = {0,0,0,0}, pd0[4] = {0,0,0,0};
    float pm1[4] = {0,0,0,0}, pq1[4] = {0,0,0,0}, pd1[4] = {0,0,0,0};
    #pragma unroll
    for (int nt = 0; nt < 8; ++nt) {
      float c0 = bb7[colbase + nt * 16 + lm];
      float w8 = cstF[colbase + nt * 16 + lm];
      #pragma unroll
      for (int i = 0; i < 4; ++i) {
        float v0 = acc0[nt][i] + c0, v1 = acc1[nt][i] + c0;
        float a0 = (v0 > 0.f) ? v0 : (__expf(v0) - 1.f);
        float a1 = (v1 > 0.f) ? v1 : (__expf(v1) - 1.f);
        pm0[i] += a0;  pq0[i] = fmaf(a0, a0, pq0[i]);  pd0[i] = fmaf(a0, w8, pd0[i]);
        pm1[i] += a1;  pq1[i] = fmaf(a1, a1, pq1[i]);  pd1[i] = fmaf(a1, w8, pd1[i]);
      }
    }
    #pragma unroll
    for (int off = 1; off < 16; off <<= 1) {
      #pragma unroll
      for (int i = 0; i < 4; ++i) {
        pm0[i] += __shfl_xor(pm0[i], off, 64);
        pq0[i] += __shfl_xor(pq0[i], off, 64);
        pd0[i] += __shfl_xor(pd0[i], off, 64);
        pm1[i] += __shfl_xor(pm1[i], off, 64);
        pq1[i] += __shfl_xor(pq1[i], off, 64);
        pd1[i] += __shfl_xor(pd1[i], off, 64);
      }
    }
    if (lm == 0) {
      #pragma unroll
      for (int i = 0; i < 4; ++i) {
        pnm[nh][R0 + lg * 4 + i] = pm0[i];
        pnq[nh][R0 + lg * 4 + i] = pq0[i];
        pdt[nh][R0 + lg * 4 + i] = pd0[i];
        pnm[nh][R0 + 16 + lg * 4 + i] = pm1[i];
        pnq[nh][R0 + 16 + lg * 4 + i] = pq1[i];
        pdt[nh][R0 + 16 + lg * 4 + i] = pd1[i];
      }
    }
    __syncthreads();
    if (nh == 0 && lm == 0) {
      #pragma unroll
      for (int tile = 0; tile < 2; ++tile) {
        #pragma unroll
        for (int i = 0; i < 4; ++i) {
          int r = R0 + tile * 16 + lg * 4 + i;
          float nm = pnm[0][r] + pnm[1][r];
          float nq = pnq[0][r] + pnq[1][r];
          float dt = pdt[0][r] + pdt[1][r];
          float mu = nm * (1.f / 256.f);
          float is = rsqrtf(nq * (1.f / 256.f) - mu * mu + EPS_LN);
          long gr = rowbase + r;
          if (gr < N_ROWS) out[gr] = fmaf(is, dt - mu * s8, cb8);
        }
      }
    }
  };

  // ================= layer 1: z1 = LN-norm(tanh(t @ W1^T + b1)), K=64 =============
  {
    #pragma unroll
    for (int i = 0; i < 8; ++i) { acc0[i] = (f32x4){0,0,0,0}; acc1[i] = (f32x4){0,0,0,0}; }
    #pragma unroll
    for (int kt = 0; kt < 2; ++kt) {
      f16x8 av0 = *(const f16x8*)&hbuf[myrow0 * 256 + ((kt * 32 + lg * 8) ^ sA0)];
      f16x8 av1 = *(const f16x8*)&hbuf[myrow1 * 256 + ((kt * 32 + lg * 8) ^ sA1)];
      #pragma unroll
      for (int nt = 0; nt < 8; ++nt) {
        int j40 = (colbase + nt * 16 + lm) * 40;
        f16x8 bf = 0;
        if (kt == 0)       bf = *(const f16x8*)&wsw[j40 + lg * 8];
        else if (lg == 0)  bf = *(const f16x8*)&wsw[j40 + 32];
        acc0[nt] = __builtin_amdgcn_mfma_f32_16x16x32_f16(av0, bf, acc0[nt], 0, 0, 0);
        acc1[nt] = __builtin_amdgcn_mfma_f32_16x16x32_f16(av1, bf, acc1[nt], 0, 0, 0);
      }
    }
    do_tile(true, b1);
  }

  // ================= layers 2..7 =================
  #pragma unroll 1
  for (int li = 0; li < 6; ++li) {
    const f16* Wb = WgBase + li * 65536;
    #pragma unroll
    for (int i = 0; i < 8; ++i) { acc0[i] = (f32x4){0,0,0,0}; acc1[i] = (f32x4){0,0,0,0}; }
    #pragma unroll 1
    for (int kt = 0; kt < 8; ++kt) {
      asm volatile("s_waitcnt vmcnt(0)" ::: "memory");   // slab kt DMA drained
      __syncthreads();                                   // visible to all waves
      __builtin_amdgcn_sched_barrier(0);
      if (kt < 7)       stage((kt + 1) & 1, Wb + (kt + 1) * 8192);
      else if (li < 5)  stage(0, Wb + 65536);
      compute(kt, wslab[kt & 1]);
    }
    if (li < 5) do_tile(false, cstF + 1536 + li * 256);
    else        final_tile();
  }
}

extern "C" void kernel_launch(void* const* d_in, const int* in_sizes, int n_in,
                              void* d_out, int out_size, void* d_ws, size_t ws_size,
                              hipStream_t stream) {
  const float* x  = (const float*)d_in[0];
  const float* W1 = (const float*)d_in[1];
  const float* b1 = (const float*)d_in[2];
  const float* W2 = (const float*)d_in[3];
  const float* b2 = (const float*)d_in[4];
  const float* W3 = (const float*)d_in[5];
  const float* b3 = (const float*)d_in[6];
  const float* W4 = (const float*)d_in[7];
  const float* b4 = (const float*)d_in[8];
  const float* W5 = (const float*)d_in[9];
  const float* b5 = (const float*)d_in[10];
  const float* W6 = (const float*)d_in[11];
  const float* b6 = (const float*)d_in[12];
  const float* W7 = (const float*)d_in[13];
  const float* b7 = (const float*)d_in[14];
  const float* W8 = (const float*)d_in[15];
  const float* b8 = (const float*)d_in[16];
  const float* gm = (const float*)d_in[17];
  const float* bt = (const float*)d_in[18];
  f16* ws = (f16*)d_ws;
  float* out = (float*)d_out;

  prep_kernel<<<1608, 256, 0, stream>>>(W1, W2, W3, W4, W5, W6, W7, W8, b8,
                                        b2, b3, b4, b5, b6, b7, gm, bt, ws);

  int nblk = (N_ROWS + 63) / 64;   // 7813
  mlp_kernel<<<nblk, 256, 0, stream>>>(x, ws, b1, out);
}

// Round 12
// 1040.965 us; speedup vs baseline: 2.1313x; 1.0006x over previous
//
#include <hip/hip_runtime.h>

typedef _Float16 f16;
typedef _Float16 f16x8 __attribute__((ext_vector_type(8)));
typedef float f32x4 __attribute__((ext_vector_type(4)));

#define N_ROWS 500000
#define EPS_LOG 1e-7f
#define EPS_LN  1e-5f

// ws layout (819200 bytes total, proven safe):
//   f16 idx [0, 10240)      : W1p [256][40]
//   bytes [20480, 32768)    : f32 cst: [0,256)=w8g, [256]=s8, [257]=cb8,
//                             [1536+li*256+j]=bb (layers 2..7)
//   f16 idx [16384, 409600) : Wg layers 2..7 slab-permuted (16KB per K-step),
//       BANK-DECORRELATED: idx = 16384 + li*65536 + kt*8192 + kgrp*2048 + jj*8 + e
//       with jj = j ^ (kgrp<<1);  value = W[j][k]*gamma[k], k = kt*32+kgrp*8+e.
//       (XOR spreads the 4 lg-groups of a wave across 4 distinct LDS banks;
//        r11 measured 8-way conflicts on this path.)
#define CST_BYTE_OFF 20480

__device__ __forceinline__ void gload_lds16(const f16* g, f16* l) {
  __builtin_amdgcn_global_load_lds(
      (const __attribute__((address_space(1))) void*)g,
      (__attribute__((address_space(3))) void*)l, 16, 0, 0);
}

// ---------------- prep ----------------
__global__ void prep_kernel(const float* __restrict__ W1,
                            const float* __restrict__ W2, const float* __restrict__ W3,
                            const float* __restrict__ W4, const float* __restrict__ W5,
                            const float* __restrict__ W6, const float* __restrict__ W7,
                            const float* __restrict__ W8, const float* __restrict__ b8,
                            const float* __restrict__ b2, const float* __restrict__ b3,
                            const float* __restrict__ b4, const float* __restrict__ b5,
                            const float* __restrict__ b6, const float* __restrict__ b7,
                            const float* __restrict__ gamma, const float* __restrict__ beta,
                            f16* __restrict__ ws) {
  float* cstF = (float*)((char*)ws + CST_BYTE_OFF);
  int idx = blockIdx.x * 256 + threadIdx.x;
  if (idx < 10240) {
    int j = idx / 40, k = idx - j * 40;
    ws[idx] = (f16)((k < 39) ? W1[j * 39 + k] : 0.0f);
  } else if (idx < 16384) {
    // cst region — written below
  } else if (idx < 409600) {
    int o = idx - 16384;
    int li = o >> 16;  o &= 65535;
    const float* W = (li == 0) ? W2 : (li == 1) ? W3 : (li == 2) ? W4
                   : (li == 3) ? W5 : (li == 4) ? W6 : W7;
    int e = o & 7, jj = (o >> 3) & 255, kgrp = (o >> 11) & 3, kt = o >> 13;
    int j = jj ^ (kgrp << 1);              // bank-decorrelating storage swizzle
    int k = kt * 32 + kgrp * 8 + e;
    ws[idx] = (f16)(W[j * 256 + k] * gamma[k]);
  } else if (idx < 411136) {
    int o = idx - 409600;
    int li = o >> 8, j = o & 255;
    const float* W = (li == 0) ? W2 : (li == 1) ? W3 : (li == 2) ? W4
                   : (li == 3) ? W5 : (li == 4) ? W6 : W7;
    const float* b = (li == 0) ? b2 : (li == 1) ? b3 : (li == 2) ? b4
                   : (li == 3) ? b5 : (li == 4) ? b6 : b7;
    float bb = 0.f;
    for (int k = 0; k < 256; ++k) bb = fmaf(W[j * 256 + k], beta[k], bb);
    cstF[1536 + li * 256 + j] = bb + b[j];
  } else if (idx < 411392) {
    int j = idx - 411136;
    cstF[j] = W8[j] * gamma[j];
  } else if (idx == 411392) {
    float s8 = 0.f, cb = 0.f;
    for (int k = 0; k < 256; ++k) {
      float w = W8[k];
      s8 = fmaf(w, gamma[k], s8);
      cb = fmaf(w, beta[k], cb);
    }
    cstF[256] = s8;
    cstF[257] = cb + b8[0];
  }
}

// ---------------- fused MLP: N-split waves, pinned 2 waves/EU (no spill) ----------
// 256 threads = 4 waves = 2 M-bands x 2 N-halves; 64 rows/block; acc = 64 regs.
// waves_per_eu(2,2): LDS caps at 2 blocks/CU anyway; pinning stops the allocator
// snapping arch regs to 128 (r11: spill 168 MB at VGPR=128 despite 192 free).
// Slab staged via global_load_lds, dbuf, r10-proven [vmcnt(0);barrier;schedbar]
// per K-step. All hbuf GEMM traffic wave-private at stride 256 (r5-proven).
__global__ __launch_bounds__(256)
__attribute__((amdgpu_waves_per_eu(2, 2)))
void mlp_kernel(const float* __restrict__ x, const f16* __restrict__ wsw,
                const float* __restrict__ b1, float* __restrict__ out) {
  __shared__ __attribute__((aligned(16))) f16 hbuf[64 * 256];    // 32 KB
  __shared__ __attribute__((aligned(16))) f16 wslab[2][8192];    // 32 KB
  __shared__ float pnm[2][64], pnq[2][64], pdt[2][64];           // 1.5 KB

  const float* cstF = (const float*)((const char*)wsw + CST_BYTE_OFF);
  const int t = threadIdx.x;
  const int lane = t & 63;
  const int wid = t >> 6;
  const int mb = wid >> 1;           // M-band 0..1
  const int nh = wid & 1;            // N-half 0..1
  const int lm = lane & 15;
  const int lg = lane >> 4;
  const long rowbase = (long)blockIdx.x * 64;
  const int R0 = mb * 32;
  const int myrow0 = R0 + lm;
  const int myrow1 = R0 + 16 + lm;
  const int sA0 = ((myrow0 >> 1) & 7) << 3;
  const int sA1 = ((myrow1 >> 1) & 7) << 3;
  const int colbase = nh * 128;

  // 16 KB slab: 256 threads x 4 chunks x 16 B (r10/r11-proven addressing)
  auto stage = [&](int buf, const f16* g) {
    #pragma unroll
    for (int c = 0; c < 4; ++c) {
      int d = c * 256 + t;
      gload_lds16(g + d * 8, &wslab[buf][d * 8]);
    }
  };

  const f16* WgBase = wsw + 16384;
  stage(0, WgBase);                  // layer-2 slab 0 in flight from the start

  // ---- input fill: rows [wid*16,+16), stride 256, swizzled, zero-padded ----
  #pragma unroll 1
  for (int i = 0; i < 16; ++i) {
    int r = wid * 16 + i;
    long gr = rowbase + r;
    float tv = 0.0f;
    if (lane < 39) {
      float xv = (gr < N_ROWS) ? x[gr * 39 + lane] : 1.0f;
      tv = 0.1f * __logf(xv + EPS_LOG);
    }
    hbuf[r * 256 + (lane ^ (((r >> 1) & 7) << 3))] = (f16)tv;
  }
  __syncthreads();                   // fill visible to all waves

  f32x4 acc0[8], acc1[8];

  auto compute = [&](int kt, const f16* wsl) {
    f16x8 av0 = *(const f16x8*)&hbuf[myrow0 * 256 + ((kt * 32 + lg * 8) ^ sA0)];
    f16x8 av1 = *(const f16x8*)&hbuf[myrow1 * 256 + ((kt * 32 + lg * 8) ^ sA1)];
    #pragma unroll
    for (int nt = 0; nt < 8; ++nt) {
      int jj = (colbase + nt * 16 + lm) ^ (lg << 1);   // match prep's storage XOR
      f16x8 bf = *(const f16x8*)&wsl[lg * 2048 + jj * 8];
      acc0[nt] = __builtin_amdgcn_mfma_f32_16x16x32_f16(av0, bf, acc0[nt], 0, 0, 0);
      acc1[nt] = __builtin_amdgcn_mfma_f32_16x16x32_f16(av1, bf, acc1[nt], 0, 0, 0);
    }
  };

  // epilogue (both M-tiles): act -> cross-half stats via LDS partials -> z-store.
  // C layout (m89): lane (lg,lm) holds acc{0,1}[nt][i] = row R0+{0,16}+lg*4+i,
  // col colbase+nt*16+lm.
  auto do_tile = [&](bool tanh_act, const float* cvec) {
    float pm0[4] = {0,0,0,0}, pq0[4] = {0,0,0,0};
    float pm1[4] = {0,0,0,0}, pq1[4] = {0,0,0,0};
    #pragma unroll
    for (int nt = 0; nt < 8; ++nt) {
      float c0 = cvec[colbase + nt * 16 + lm];
      #pragma unroll
      for (int i = 0; i < 4; ++i) {
        float v0 = acc0[nt][i] + c0, v1 = acc1[nt][i] + c0;
        float a0, a1;
        if (tanh_act) {
          float e0 = __expf(2.f * v0), e1 = __expf(2.f * v1);
          a0 = 1.f - 2.f / (e0 + 1.f);
          a1 = 1.f - 2.f / (e1 + 1.f);
        } else {
          a0 = (v0 > 0.f) ? v0 : (__expf(v0) - 1.f);
          a1 = (v1 > 0.f) ? v1 : (__expf(v1) - 1.f);
        }
        acc0[nt][i] = a0;  acc1[nt][i] = a1;
        pm0[i] += a0;  pq0[i] = fmaf(a0, a0, pq0[i]);
        pm1[i] += a1;  pq1[i] = fmaf(a1, a1, pq1[i]);
      }
    }
    #pragma unroll
    for (int off = 1; off < 16; off <<= 1) {
      #pragma unroll
      for (int i = 0; i < 4; ++i) {
        pm0[i] += __shfl_xor(pm0[i], off, 64);
        pq0[i] += __shfl_xor(pq0[i], off, 64);
        pm1[i] += __shfl_xor(pm1[i], off, 64);
        pq1[i] += __shfl_xor(pq1[i], off, 64);
      }
    }
    if (lm == 0) {
      #pragma unroll
      for (int i = 0; i < 4; ++i) {
        pnm[nh][R0 + lg * 4 + i] = pm0[i];
        pnq[nh][R0 + lg * 4 + i] = pq0[i];
        pnm[nh][R0 + 16 + lg * 4 + i] = pm1[i];
        pnq[nh][R0 + 16 + lg * 4 + i] = pq1[i];
      }
    }
    __syncthreads();                 // both halves' partials visible
    float mu0[4], is0[4], mu1[4], is1[4];
    #pragma unroll
    for (int i = 0; i < 4; ++i) {
      int r0 = R0 + lg * 4 + i, r1 = r0 + 16;
      float m0 = (pnm[0][r0] + pnm[1][r0]) * (1.f / 256.f);
      float m1 = (pnm[0][r1] + pnm[1][r1]) * (1.f / 256.f);
      float q0 = (pnq[0][r0] + pnq[1][r0]) * (1.f / 256.f);
      float q1 = (pnq[0][r1] + pnq[1][r1]) * (1.f / 256.f);
      mu0[i] = m0;  is0[i] = rsqrtf(q0 - m0 * m0 + EPS_LN);
      mu1[i] = m1;  is1[i] = rsqrtf(q1 - m1 * m1 + EPS_LN);
    }
    #pragma unroll
    for (int nt = 0; nt < 8; ++nt) {
      int col = colbase + nt * 16 + lm;
      #pragma unroll
      for (int i = 0; i < 4; ++i) {
        int r0 = R0 + lg * 4 + i, r1 = r0 + 16;
        hbuf[r0 * 256 + (col ^ (((r0 >> 1) & 7) << 3))] =
            (f16)((acc0[nt][i] - mu0[i]) * is0[i]);
        hbuf[r1 * 256 + (col ^ (((r1 >> 1) & 7) << 3))] =
            (f16)((acc1[nt][i] - mu1[i]) * is1[i]);
      }
    }
  };

  // layer-7 epilogue fused with layer 8: out = is*(dot - mu*s8) + cb8
  auto final_tile = [&]() {
    const float* bb7 = cstF + 1536 + 5 * 256;
    float s8 = cstF[256], cb8 = cstF[257];
    float pm0[4] = {0,0,0,0}, pq0[4] = {0,0,0,0}, pd0[4] = {0,0,0,0};
    float pm1[4] = {0,0,0,0}, pq1[4] = {0,0,0,0}, pd1[4] = {0,0,0,0};
    #pragma unroll
    for (int nt = 0; nt < 8; ++nt) {
      float c0 = bb7[colbase + nt * 16 + lm];
      float w8 = cstF[colbase + nt * 16 + lm];
      #pragma unroll
      for (int i = 0; i < 4; ++i) {
        float v0 = acc0[nt][i] + c0, v1 = acc1[nt][i] + c0;
        float a0 = (v0 > 0.f) ? v0 : (__expf(v0) - 1.f);
        float a1 = (v1 > 0.f) ? v1 : (__expf(v1) - 1.f);
        pm0[i] += a0;  pq0[i] = fmaf(a0, a0, pq0[i]);  pd0[i] = fmaf(a0, w8, pd0[i]);
        pm1[i] += a1;  pq1[i] = fmaf(a1, a1, pq1[i]);  pd1[i] = fmaf(a1, w8, pd1[i]);
      }
    }
    #pragma unroll
    for (int off = 1; off < 16; off <<= 1) {
      #pragma unroll
      for (int i = 0; i < 4; ++i) {
        pm0[i] += __shfl_xor(pm0[i], off, 64);
        pq0[i] += __shfl_xor(pq0[i], off, 64);
        pd0[i] += __shfl_xor(pd0[i], off, 64);
        pm1[i] += __shfl_xor(pm1[i], off, 64);
        pq1[i] += __shfl_xor(pq1[i], off, 64);
        pd1[i] += __shfl_xor(pd1[i], off, 64);
      }
    }
    if (lm == 0) {
      #pragma unroll
      for (int i = 0; i < 4; ++i) {
        pnm[nh][R0 + lg * 4 + i] = pm0[i];
        pnq[nh][R0 + lg * 4 + i] = pq0[i];
        pdt[nh][R0 + lg * 4 + i] = pd0[i];
        pnm[nh][R0 + 16 + lg * 4 + i] = pm1[i];
        pnq[nh][R0 + 16 + lg * 4 + i] = pq1[i];
        pdt[nh][R0 + 16 + lg * 4 + i] = pd1[i];
      }
    }
    __syncthreads();
    if (nh == 0 && lm == 0) {
      #pragma unroll
      for (int tile = 0; tile < 2; ++tile) {
        #pragma unroll
        for (int i = 0; i < 4; ++i) {
          int r = R0 + tile * 16 + lg * 4 + i;
          float nm = pnm[0][r] + pnm[1][r];
          float nq = pnq[0][r] + pnq[1][r];
          float dt = pdt[0][r] + pdt[1][r];
          float mu = nm * (1.f / 256.f);
          float is = rsqrtf(nq * (1.f / 256.f) - mu * mu + EPS_LN);
          long gr = rowbase + r;
          if (gr < N_ROWS) out[gr] = fmaf(is, dt - mu * s8, cb8);
        }
      }
    }
  };

  // ================= layer 1: z1 = LN-norm(tanh(t @ W1^T + b1)), K=64 =============
  {
    #pragma unroll
    for (int i = 0; i < 8; ++i) { acc0[i] = (f32x4){0,0,0,0}; acc1[i] = (f32x4){0,0,0,0}; }
    #pragma unroll
    for (int kt = 0; kt < 2; ++kt) {
      f16x8 av0 = *(const f16x8*)&hbuf[myrow0 * 256 + ((kt * 32 + lg * 8) ^ sA0)];
      f16x8 av1 = *(const f16x8*)&hbuf[myrow1 * 256 + ((kt * 32 + lg * 8) ^ sA1)];
      #pragma unroll
      for (int nt = 0; nt < 8; ++nt) {
        int j40 = (colbase + nt * 16 + lm) * 40;
        f16x8 bf = 0;
        if (kt == 0)       bf = *(const f16x8*)&wsw[j40 + lg * 8];
        else if (lg == 0)  bf = *(const f16x8*)&wsw[j40 + 32];
        acc0[nt] = __builtin_amdgcn_mfma_f32_16x16x32_f16(av0, bf, acc0[nt], 0, 0, 0);
        acc1[nt] = __builtin_amdgcn_mfma_f32_16x16x32_f16(av1, bf, acc1[nt], 0, 0, 0);
      }
    }
    do_tile(true, b1);
  }

  // ================= layers 2..7 =================
  #pragma unroll 1
  for (int li = 0; li < 6; ++li) {
    const f16* Wb = WgBase + li * 65536;
    #pragma unroll
    for (int i = 0; i < 8; ++i) { acc0[i] = (f32x4){0,0,0,0}; acc1[i] = (f32x4){0,0,0,0}; }
    #pragma unroll 1
    for (int kt = 0; kt < 8; ++kt) {
      asm volatile("s_waitcnt vmcnt(0)" ::: "memory");   // slab kt DMA drained
      __syncthreads();                                   // visible to all waves
      __builtin_amdgcn_sched_barrier(0);
      if (kt < 7)       stage((kt + 1) & 1, Wb + (kt + 1) * 8192);
      else if (li < 5)  stage(0, Wb + 65536);
      compute(kt, wslab[kt & 1]);
    }
    if (li < 5) do_tile(false, cstF + 1536 + li * 256);
    else        final_tile();
  }
}

extern "C" void kernel_launch(void* const* d_in, const int* in_sizes, int n_in,
                              void* d_out, int out_size, void* d_ws, size_t ws_size,
                              hipStream_t stream) {
  const float* x  = (const float*)d_in[0];
  const float* W1 = (const float*)d_in[1];
  const float* b1 = (const float*)d_in[2];
  const float* W2 = (const float*)d_in[3];
  const float* b2 = (const float*)d_in[4];
  const float* W3 = (const float*)d_in[5];
  const float* b3 = (const float*)d_in[6];
  const float* W4 = (const float*)d_in[7];
  const float* b4 = (const float*)d_in[8];
  const float* W5 = (const float*)d_in[9];
  const float* b5 = (const float*)d_in[10];
  const float* W6 = (const float*)d_in[11];
  const float* b6 = (const float*)d_in[12];
  const float* W7 = (const float*)d_in[13];
  const float* b7 = (const float*)d_in[14];
  const float* W8 = (const float*)d_in[15];
  const float* b8 = (const float*)d_in[16];
  const float* gm = (const float*)d_in[17];
  const float* bt = (const float*)d_in[18];
  f16* ws = (f16*)d_ws;
  float* out = (float*)d_out;

  prep_kernel<<<1608, 256, 0, stream>>>(W1, W2, W3, W4, W5, W6, W7, W8, b8,
                                        b2, b3, b4, b5, b6, b7, gm, bt, ws);

  int nblk = (N_ROWS + 63) / 64;   // 7813
  mlp_kernel<<<nblk, 256, 0, stream>>>(x, ws, b1, out);
}